// Round 1
// 7707.989 us; speedup vs baseline: 1.0846x; 1.0846x over previous
//
#include <hip/hip_runtime.h>
#include <hip/hip_bf16.h>
#include <cstdio>
#include <cstdint>

// MultilayerGRU: B=32, S=512, I=H=O=1024, L=2
// R5: fused two-layer pipeline. Both layer recurrences run concurrently in
// one 256-block persistent kernel (layer = blockIdx>>7, 1 block/CU). Layer0
// publishes h0(t) to hist0 with agent-scope stores + flH epoch flags (flag
// deferred to after the loop-bottom barrier, which already drains vmcnt, so
// layer0's critical path is unchanged). Layer1 stages h0(t) into LDS and
// computes its input projections in-kernel (x-weights resident in VGPRs,
// accumulating into the same MFMA accumulators as the recurrent part),
// eliminating the 3 intermediate GEMMs and the serial layer barrier.

typedef float f32x4 __attribute__((ext_vector_type(4)));
typedef __bf16 bf16x8 __attribute__((ext_vector_type(8)));
typedef unsigned short u16;

#define AS1 __attribute__((address_space(1)))
#define AS3 __attribute__((address_space(3)))

__device__ inline u16 f2b(float f) {
  __hip_bfloat16 h = __float2bfloat16(f);
  return *reinterpret_cast<u16*>(&h);
}
__device__ inline float b2f(u16 u) {
  __hip_bfloat16 h;
  *reinterpret_cast<u16*>(&h) = u;
  return __bfloat162float(h);
}
__device__ inline bf16x8 ld8(const u16* p) {
  return *reinterpret_cast<const bf16x8*>(p);
}
__device__ inline f32x4 mfma16(bf16x8 a, bf16x8 b, f32x4 c) {
  return __builtin_amdgcn_mfma_f32_16x16x32_bf16(a, b, c, 0, 0, 0);
}

// plain (L2-cacheable) global->LDS DMA, 16B/lane
__device__ inline void gload_lds16(const void* g, void* l) {
  __builtin_amdgcn_global_load_lds((const AS1 void*)g, (AS3 void*)l, 16, 0, 0);
}
// agent-scope global->LDS DMA (CPol SC1 only = device scope): bypasses the
// potentially-stale per-XCD L2 but is served by the LLC (agent coherence pt).
__device__ inline void gload_lds16c(const void* g, void* l) {
  __builtin_amdgcn_global_load_lds((const AS1 void*)g, (AS3 void*)l, 16, 0, 0x10);
}

// relaxed agent-scope (LLC write-through) u16 store
__device__ inline void st16(u16* p, u16 v) {
  __hip_atomic_store(p, v, __ATOMIC_RELAXED, __HIP_MEMORY_SCOPE_AGENT);
}

// 64 lanes watch 64 packed epoch flags; exit when all >= target
__device__ inline void poll64(unsigned* f, unsigned target, int lane) {
  unsigned* p = f + lane;
  while (true) {
    unsigned v = __hip_atomic_load(p, __ATOMIC_RELAXED, __HIP_MEMORY_SCOPE_AGENT);
    if (__all((int)(v >= target))) break;
    __builtin_amdgcn_s_sleep(1);
  }
}

// combined two-flag-array poll (one LLC round trip for both conditions)
__device__ inline void poll64x2(unsigned* fa, unsigned ta, unsigned* fb,
                                unsigned tb, int lane) {
  unsigned* pa = fa + lane;
  unsigned* pb = fb + lane;
  while (true) {
    unsigned va = __hip_atomic_load(pa, __ATOMIC_RELAXED, __HIP_MEMORY_SCOPE_AGENT);
    unsigned vb = __hip_atomic_load(pb, __ATOMIC_RELAXED, __HIP_MEMORY_SCOPE_AGENT);
    if (__all((int)(va >= ta) & (int)(vb >= tb))) break;
    __builtin_amdgcn_s_sleep(1);
  }
}

// ---------------- elementwise helpers ----------------

__global__ void castk(const float* __restrict__ src, u16* __restrict__ dst, int n) {
  int i = blockIdx.x * 256 + threadIdx.x;
  if (i < n) dst[i] = f2b(src[i]);
}

__global__ void init_h(const float* __restrict__ h0, float* __restrict__ h32_0,
                       float* __restrict__ h32_1, u16* __restrict__ hbf_0,
                       u16* __restrict__ hbf_1) {
  int i = blockIdx.x * 256 + threadIdx.x;
  if (i < 32 * 1024) {
    int b = i >> 10, j = i & 1023;
    float v0 = h0[(b * 2 + 0) * 1024 + j];
    float v1 = h0[(b * 2 + 1) * 1024 + j];
    h32_0[i] = v0; hbf_0[i] = f2b(v0);
    h32_1[i] = v1; hbf_1[i] = f2b(v1);
  }
}

__global__ void final_h(const float* __restrict__ h32_0, const float* __restrict__ h32_1,
                        float* __restrict__ out) {
  int i = blockIdx.x * 256 + threadIdx.x;
  if (i < 32 * 1024) {
    int b = i >> 10, j = i & 1023;
    out[(b * 2 + 0) * 1024 + j] = h32_0[i];
    out[(b * 2 + 1) * 1024 + j] = h32_1[i];
  }
}

// ---------------- big NT GEMM: C[m,n] = sum_k A[m,k]*B[n,k] + bias[n] ----------------
// MODE 0: fp32 store at [m][n].  MODE 2: bf16 store transposed-to-step-major:
// m = b*512 + t  ->  store at [(t*32 + b)][n]  (A buffers for the recurrence).

template <int MODE>
__global__ __launch_bounds__(256, 2) void gemm_nt(const u16* __restrict__ A,
                                                  const u16* __restrict__ B,
                                                  const float* __restrict__ bias,
                                                  void* __restrict__ Cout,
                                                  int M, int N, int K) {
  __shared__ __align__(16) u16 As[128 * 32];
  __shared__ __align__(16) u16 Bs[128 * 32];
  const int tid = threadIdx.x;
  const int lane = tid & 63;
  const int wave = tid >> 6;
  const int tilesN = N >> 7;
  const int bm = blockIdx.x / tilesN, bn = blockIdx.x % tilesN;
  const int wr = (wave >> 1) << 6, wc = (wave & 1) << 6;
  const int la = lane & 15, kg = lane >> 4;
  f32x4 acc[4][4] = {};
  const int srow = tid >> 2, skoff = (tid & 3) << 3;
  const u16* Ap = A + (size_t)(bm * 128 + srow) * K + skoff;
  const u16* Bp = B + (size_t)(bn * 128 + srow) * K + skoff;
  for (int k0 = 0; k0 < K; k0 += 32) {
    gload_lds16(Ap + k0,            As + tid * 8);
    gload_lds16(Ap + (size_t)64 * K + k0, As + 2048 + tid * 8);
    gload_lds16(Bp + k0,            Bs + tid * 8);
    gload_lds16(Bp + (size_t)64 * K + k0, Bs + 2048 + tid * 8);
    __syncthreads();
    bf16x8 af[4], bfr[4];
#pragma unroll
    for (int i = 0; i < 4; ++i) af[i] = ld8(As + (wr + i * 16 + la) * 32 + kg * 8);
#pragma unroll
    for (int j = 0; j < 4; ++j) bfr[j] = ld8(Bs + (wc + j * 16 + la) * 32 + kg * 8);
#pragma unroll
    for (int i = 0; i < 4; ++i)
#pragma unroll
      for (int j = 0; j < 4; ++j)
        acc[i][j] = mfma16(af[i], bfr[j], acc[i][j]);
    __syncthreads();
  }
  const int rbase = bm * 128 + wr + kg * 4;
  const int cbase = bn * 128 + wc + la;
#pragma unroll
  for (int i = 0; i < 4; ++i) {
#pragma unroll
    for (int j = 0; j < 4; ++j) {
      int col = cbase + j * 16;
      float bv = bias[col];
#pragma unroll
      for (int e = 0; e < 4; ++e) {
        int row = rbase + i * 16 + e;
        float v = acc[i][j][e] + bv;
        if (MODE == 0) {
          ((float*)Cout)[(size_t)row * N + col] = v;
        } else {
          int tt = row & 511, bb = row >> 9;
          ((u16*)Cout)[((size_t)(tt * 32 + bb)) * N + col] = f2b(v);
        }
      }
    }
  }
}

// ---------------- fused two-layer persistent GRU recurrence ----------------
// 256 blocks x 128 threads: layer = bid>>7, rt = (bid>>6)&1, colT = bid&63.
// Layer0: identical structure to the proven gru_layer4 (A-buffers from the
//   precomputed x GEMMs), except hist0 stores are agent-scope and flH[colT]
//   is published at the TOP of the next iteration (hist stores were drained
//   by the loop-bottom barrier's implicit vmcnt(0) -> zero added drain).
// Layer1: per step, combined-poll {fl2>=t, flH>=t+1}, DMA h0(t)->LDSx and
//   h1(t-1)->LDSh back-to-back (both in flight, one barrier), then z/r =
//   32 rec MFMA (LDSh,wzr) + 32 xproj MFMA (LDSx,wzx) into the same
//   accumulators; stage2 g = split-K rec (LDSh=rh,wg) + split-K xproj
//   (LDSx,wgx). Biases added as scalars.

__global__ __launch_bounds__(128, 1) void gru_pipe(
    const u16* __restrict__ Wz0, const u16* __restrict__ Wr0, const u16* __restrict__ Wg0,
    const u16* __restrict__ Wz1, const u16* __restrict__ Wr1, const u16* __restrict__ Wg1,
    const u16* __restrict__ Wzx1, const u16* __restrict__ Wrx1, const u16* __restrict__ Wgx1,
    const float* __restrict__ bz1, const float* __restrict__ br1, const float* __restrict__ bg1,
    const u16* __restrict__ Az, const u16* __restrict__ Ar, const u16* __restrict__ Ag,
    u16* __restrict__ hist0, u16* __restrict__ hist1,
    float* __restrict__ h32_0, float* __restrict__ h32_1,
    u16* __restrict__ hbf0, u16* __restrict__ hbf1,
    u16* __restrict__ rhbf0, u16* __restrict__ rhbf1,
    unsigned* __restrict__ flags, int S) {
  __shared__ __align__(16) u16 LDSh[16 * 1024];
  __shared__ __align__(16) u16 LDSx[16 * 1024];
  __shared__ float zloc[256];
  __shared__ float h32loc[256];
  __shared__ float part[256];
  const int tid = threadIdx.x, wave = tid >> 6, lane = tid & 63;
  const int la = lane & 15, kg = lane >> 4;
  const int sw = la & 7;
  const int layer = blockIdx.x >> 7;
  const int rt = (blockIdx.x >> 6) & 1, colT = blockIdx.x & 63;
  const int col = colT * 16 + la;
  unsigned* fl1 = flags + (layer * 2 + rt) * 128;  // stage1 (rhbf ready) epochs
  unsigned* fl2 = fl1 + 64;                        // stage2 (h ready) epochs
  unsigned* flH = flags + 512 + rt * 64;           // layer0 h0(t) ready epochs

  float* h32g = layer ? h32_1 : h32_0;
  u16* hbf  = layer ? hbf1 : hbf0;
  u16* rhbf = layer ? rhbf1 : rhbf0;
  u16* hist = layer ? hist1 : hist0;

  for (int i = tid; i < 256; i += 128)
    h32loc[i] = h32g[(rt * 16 + (i >> 4)) * 1024 + colT * 16 + (i & 15)];
  __syncthreads();

  // recurrent weight slices -> VGPRs (wave0: z, wave1: r; g split-K)
  const u16* w1p = (wave ? (layer ? Wr1 : Wr0) : (layer ? Wz1 : Wz0)) +
                   (size_t)col * 1024 + kg * 8;
  const u16* wgp = (layer ? Wg1 : Wg0) + (size_t)col * 1024 + wave * 512 + kg * 8;
  bf16x8 wzr[32], wg[16];
#pragma unroll
  for (int ks = 0; ks < 32; ++ks) wzr[ks] = ld8(w1p + ks * 32);
#pragma unroll
  for (int ks = 0; ks < 16; ++ks) wg[ks] = ld8(wgp + ks * 32);

  // layer1-only: input-projection weight slices + biases
  bf16x8 wzx[32], wgx[16];
  float b1v = 0.f, bgv = 0.f;
  if (layer) {
    const u16* wxp = (wave ? Wrx1 : Wzx1) + (size_t)col * 1024 + kg * 8;
    const u16* wgxp = Wgx1 + (size_t)col * 1024 + wave * 512 + kg * 8;
#pragma unroll
    for (int ks = 0; ks < 32; ++ks) wzx[ks] = ld8(wxp + ks * 32);
#pragma unroll
    for (int ks = 0; ks < 16; ++ks) wgx[ks] = ld8(wgxp + ks * 32);
    b1v = wave ? br1[col] : bz1[col];
    bgv = bg1[col];
  }

  const u16* A1 = wave ? Ar : Az;
  const u16* hsrc = hbf + rt * 16 * 1024;
  const u16* rsrc = rhbf + rt * 16 * 1024;
  const int rowb = rt * 16 + kg * 4;  // batch-row base of this lane's outputs

  for (int t = 0; t < S; ++t) {
    u16 a1raw[4] = {0, 0, 0, 0};
    u16 agraw[4] = {0, 0, 0, 0};
    if (!layer) {
      // publish h0(t-1)-ready: prev iteration's hist st16s were drained by
      // the loop-bottom barrier's vmcnt(0) -> relaxed store is safe here.
      if (t && wave == 0 && lane == 0)
        __hip_atomic_store(&flH[colT], (unsigned)t, __ATOMIC_RELAXED,
                           __HIP_MEMORY_SCOPE_AGENT);
      // A prefetch: independent of flags, overlaps poll+staging
      const u16* A1t = A1 + (size_t)t * 32768;
#pragma unroll
      for (int e = 0; e < 4; ++e) a1raw[e] = A1t[(rowb + e) * 1024 + col];
      if (wave == 0) {
        const u16* Agt = Ag + (size_t)t * 32768;
#pragma unroll
        for (int e = 0; e < 4; ++e) agraw[e] = Agt[(rowb + e) * 1024 + col];
      }
      poll64(fl2, (unsigned)t, lane);
    } else {
      // one combined poll, then both tiles' DMAs issue back-to-back
      poll64x2(fl2, (unsigned)t, flH, (unsigned)(t + 1), lane);
#pragma unroll
      for (int i = 0; i < 16; ++i) {
        int u = i * 2 + wave, r = u >> 1, c = u & 1;
        gload_lds16c(hist0 + ((size_t)(rt * 16 + r) * S + t) * 1024 + c * 512 +
                         ((lane ^ (r & 7)) * 8),
                     LDSx + r * 1024 + c * 512 + lane * 8);
      }
    }
    // ---- stage 1: z (wave0) and r (wave1) ----
#pragma unroll
    for (int i = 0; i < 16; ++i) {
      int u = i * 2 + wave, r = u >> 1, c = u & 1;
      gload_lds16c(hsrc + r * 1024 + c * 512 + (lane ^ (r & 7)) * 8,
                   LDSh + r * 1024 + c * 512 + lane * 8);
    }
    __syncthreads();  // drains all DMA (vmcnt) for both waves
    f32x4 p0 = {0.f, 0.f, 0.f, 0.f}, p1 = {0.f, 0.f, 0.f, 0.f};
#pragma unroll
    for (int ks = 0; ks < 32; ks += 2) {
      p0 = mfma16(ld8(LDSh + la * 1024 + (((ks * 4 + kg) ^ sw) << 3)), wzr[ks], p0);
      p1 = mfma16(ld8(LDSh + la * 1024 + ((((ks + 1) * 4 + kg) ^ sw) << 3)), wzr[ks + 1], p1);
    }
    if (layer) {
#pragma unroll
      for (int ks = 0; ks < 32; ks += 2) {
        p0 = mfma16(ld8(LDSx + la * 1024 + (((ks * 4 + kg) ^ sw) << 3)), wzx[ks], p0);
        p1 = mfma16(ld8(LDSx + la * 1024 + ((((ks + 1) * 4 + kg) ^ sw) << 3)), wzx[ks + 1], p1);
      }
    }
    if (wave == 0) {
#pragma unroll
      for (int e = 0; e < 4; ++e) {
        float pre = p0[e] + p1[e] + (layer ? b1v : b2f(a1raw[e]));
        zloc[(kg * 4 + e) * 16 + la] = 1.f / (1.f + __expf(-pre));
      }
    } else {
#pragma unroll
      for (int e = 0; e < 4; ++e) {
        float pre = p0[e] + p1[e] + (layer ? b1v : b2f(a1raw[e]));
        float rv = 1.f / (1.f + __expf(-pre));
        st16(&rhbf[(rowb + e) * 1024 + col], f2b(rv * h32loc[(kg * 4 + e) * 16 + la]));
      }
      __builtin_amdgcn_s_waitcnt(0);  // r-tile drained to LLC
      if (lane == 0)
        __hip_atomic_store(&fl1[colT], (unsigned)(t + 1), __ATOMIC_RELAXED,
                           __HIP_MEMORY_SCOPE_AGENT);
    }
    __syncthreads();  // wave0 must not DMA over LDSh while wave1 still reads it
    // ---- stage 2: g (split-K over both waves) + h update (wave0) ----
    poll64(fl1, (unsigned)(t + 1), lane);
#pragma unroll
    for (int i = 0; i < 16; ++i) {
      int u = i * 2 + wave, r = u >> 1, c = u & 1;
      gload_lds16c(rsrc + r * 1024 + c * 512 + (lane ^ (r & 7)) * 8,
                   LDSh + r * 1024 + c * 512 + lane * 8);
    }
    __syncthreads();
    f32x4 q0 = {0.f, 0.f, 0.f, 0.f}, q1 = {0.f, 0.f, 0.f, 0.f};
#pragma unroll
    for (int ks = 0; ks < 16; ks += 2) {
      q0 = mfma16(ld8(LDSh + la * 1024 + (((wave * 64 + ks * 4 + kg) ^ sw) << 3)), wg[ks], q0);
      q1 = mfma16(ld8(LDSh + la * 1024 + (((wave * 64 + (ks + 1) * 4 + kg) ^ sw) << 3)), wg[ks + 1], q1);
    }
    if (layer) {
#pragma unroll
      for (int ks = 0; ks < 16; ks += 2) {
        q0 = mfma16(ld8(LDSx + la * 1024 + (((wave * 64 + ks * 4 + kg) ^ sw) << 3)), wgx[ks], q0);
        q1 = mfma16(ld8(LDSx + la * 1024 + (((wave * 64 + (ks + 1) * 4 + kg) ^ sw) << 3)), wgx[ks + 1], q1);
      }
    }
    if (wave == 1) {
#pragma unroll
      for (int e = 0; e < 4; ++e) part[lane * 4 + e] = q0[e] + q1[e];
    }
    __syncthreads();
    if (wave == 0) {
      float hnv[4];
      u16 hbv[4];
#pragma unroll
      for (int e = 0; e < 4; ++e) {
        int li = (kg * 4 + e) * 16 + la;
        float gs = q0[e] + q1[e] + part[lane * 4 + e] + (layer ? bgv : b2f(agraw[e]));
        float ex = __expf(2.f * gs);
        float g = 1.f - 2.f / (ex + 1.f);  // tanh, inf-safe
        float z = zloc[li];
        float hn = (1.f - z) * h32loc[li] + z * g;
        h32loc[li] = hn;
        hnv[e] = hn;
        hbv[e] = f2b(hn);
        st16(&hbf[(rowb + e) * 1024 + col], hbv[e]);  // critical-path publish
      }
      __builtin_amdgcn_s_waitcnt(0);  // h-tile (hbf only) drained to LLC
      if (lane == 0)
        __hip_atomic_store(&fl2[colT], (unsigned)(t + 1), __ATOMIC_RELAXED,
                           __HIP_MEMORY_SCOPE_AGENT);
      // off-critical-path: history + final-state snapshot. Layer0's hist is
      // consumed in-kernel by layer1 -> agent-scope stores (drained by the
      // loop-bottom barrier; flH published next iteration). Layer1's hist is
      // only read by the later output GEMM -> plain stores suffice.
#pragma unroll
      for (int e = 0; e < 4; ++e) {
        size_t hidx = ((size_t)(rowb + e) * S + t) * 1024 + col;
        if (layer) hist[hidx] = hbv[e];
        else st16(&hist[hidx], hbv[e]);
        if (t == S - 1) h32g[(rowb + e) * 1024 + col] = hnv[e];
      }
    }
    __syncthreads();  // next stage1 DMA must not overwrite LDSh/LDSx early
  }
  // final h0(S-1) publish (hist stores drained by last loop-bottom barrier)
  if (!layer && wave == 0 && lane == 0)
    __hip_atomic_store(&flH[colT], (unsigned)S, __ATOMIC_RELAXED,
                       __HIP_MEMORY_SCOPE_AGENT);
}

// ---------------- host ----------------

extern "C" void kernel_launch(void* const* d_in, const int* in_sizes, int n_in,
                              void* d_out, int out_size, void* d_ws, size_t ws_size,
                              hipStream_t stream) {
  (void)in_sizes; (void)n_in; (void)out_size;
  const float* x   = (const float*)d_in[0];
  const float* h0  = (const float*)d_in[1];
  const float* Wzx = (const float*)d_in[2];
  const float* bz  = (const float*)d_in[3];
  const float* Wzh = (const float*)d_in[4];
  const float* Wrx = (const float*)d_in[5];
  const float* br  = (const float*)d_in[6];
  const float* Wrh = (const float*)d_in[7];
  const float* Wgx = (const float*)d_in[8];
  const float* bg  = (const float*)d_in[9];
  const float* Wgh = (const float*)d_in[10];
  const float* Wo  = (const float*)d_in[11];
  const float* bo  = (const float*)d_in[12];
  float* out = (float*)d_out;
  char* ws = (char*)d_ws;

  const size_t MB = 1024 * 1024;
  size_t o = 4096;  // flags live in [0,4096): per-(layer,rt) fl1/fl2 + flH
  u16* wWzx = (u16*)(ws + o); o += 4 * MB;   // [L=2][1024][1024] bf16
  u16* wWzh = (u16*)(ws + o); o += 4 * MB;
  u16* wWrx = (u16*)(ws + o); o += 4 * MB;
  u16* wWrh = (u16*)(ws + o); o += 4 * MB;
  u16* wWgx = (u16*)(ws + o); o += 4 * MB;
  u16* wWgh = (u16*)(ws + o); o += 4 * MB;
  u16* wWo  = (u16*)(ws + o); o += 2 * MB;
  u16* Az    = (u16*)(ws + o); o += 32 * MB;  // [512][32][1024] bf16 step-major
  u16* Ar    = (u16*)(ws + o); o += 32 * MB;
  u16* Ag    = (u16*)(ws + o); o += 32 * MB;
  u16* hist0 = (u16*)(ws + o); o += 32 * MB;  // [b*S+t][1024]
  u16* xbf   = (u16*)(ws + o); o += 32 * MB;  // x bf16; later reused as hist1
  float* h32_0 = (float*)(ws + o); o += 131072;
  float* h32_1 = (float*)(ws + o); o += 131072;
  u16* hbf_0 = (u16*)(ws + o); o += 65536;
  u16* hbf_1 = (u16*)(ws + o); o += 65536;
  u16* rhbf0 = (u16*)(ws + o); o += 65536;
  u16* rhbf1 = (u16*)(ws + o); o += 65536;

  if (ws_size < o) {
    fprintf(stderr, "[gru] INSUFFICIENT WORKSPACE ws=%zu need=%zu\n", ws_size, o);
    return;
  }
  unsigned* flags = (unsigned*)ws;
  hipMemsetAsync(ws, 0, 4096, stream);

  // casts
  castk<<<dim3(8192), dim3(256), 0, stream>>>(Wzx, wWzx, 2097152);
  castk<<<dim3(8192), dim3(256), 0, stream>>>(Wzh, wWzh, 2097152);
  castk<<<dim3(8192), dim3(256), 0, stream>>>(Wrx, wWrx, 2097152);
  castk<<<dim3(8192), dim3(256), 0, stream>>>(Wrh, wWrh, 2097152);
  castk<<<dim3(8192), dim3(256), 0, stream>>>(Wgx, wWgx, 2097152);
  castk<<<dim3(8192), dim3(256), 0, stream>>>(Wgh, wWgh, 2097152);
  castk<<<dim3(4096), dim3(256), 0, stream>>>(Wo, wWo, 1048576);
  castk<<<dim3(65536), dim3(256), 0, stream>>>(x, xbf, 16777216);
  init_h<<<dim3(128), dim3(256), 0, stream>>>(h0, h32_0, h32_1, hbf_0, hbf_1);

  // layer0 input projections (step-major output)
  gemm_nt<2><<<dim3(1024), dim3(256), 0, stream>>>(xbf, wWzx, bz, Az, 16384, 1024, 1024);
  gemm_nt<2><<<dim3(1024), dim3(256), 0, stream>>>(xbf, wWrx, br, Ar, 16384, 1024, 1024);
  gemm_nt<2><<<dim3(1024), dim3(256), 0, stream>>>(xbf, wWgx, bg, Ag, 16384, 1024, 1024);

  // fused two-layer recurrence pipeline (hist1 lives in xbf region)
  gru_pipe<<<dim3(256), dim3(128), 0, stream>>>(
      wWzh, wWrh, wWgh,
      wWzh + 1048576, wWrh + 1048576, wWgh + 1048576,
      wWzx + 1048576, wWrx + 1048576, wWgx + 1048576,
      bz + 1024, br + 1024, bg + 1024,
      Az, Ar, Ag, hist0, xbf,
      h32_0, h32_1, hbf_0, hbf_1, rhbf0, rhbf1,
      flags, 512);

  // output projection
  gemm_nt<0><<<dim3(1024), dim3(256), 0, stream>>>(xbf, wWo, bo, out, 16384, 1024, 1024);

  // final hidden states
  final_h<<<dim3(128), dim3(256), 0, stream>>>(h32_0, h32_1, out + 16777216);
}

// Round 2
// 6541.145 us; speedup vs baseline: 1.2781x; 1.1784x over previous
//
#include <hip/hip_runtime.h>
#include <hip/hip_bf16.h>
#include <cstdio>
#include <cstdint>

// MultilayerGRU: B=32, S=512, I=H=O=1024, L=2
// R6: fused two-layer pipeline, v2.
//  - Layer1's stage-1 x-projection weights moved to LDS (64 KB, one-time
//    staged, per-lane-contiguous = conflict-free ds_read_b128): register
//    pressure back to ~R4 levels (R5 hit the 256-VGPR cap and paid
//    AGPR/scratch shuffles inside layer1's MFMA loops -> 13.9 us/step).
//  - hist0 + flH eliminated: layer0 publishes h(t) into a 4-deep ring
//    hring[4][32][1024]; fl2(L0) doubles as the cross-layer flag, so layer1
//    sees h0(t) at the same instant layer0's own step t+1 can start
//    (removes one step of pipeline lag, one flag publish, 32 MB of agent
//    writes and the scattered hist0 reads). Ring overrun prevented by
//    layer0 gating on fl1(L1) >= t-3 (lag <= 4; wait graph is acyclic).

typedef float f32x4 __attribute__((ext_vector_type(4)));
typedef __bf16 bf16x8 __attribute__((ext_vector_type(8)));
typedef unsigned short u16;

#define AS1 __attribute__((address_space(1)))
#define AS3 __attribute__((address_space(3)))

__device__ inline u16 f2b(float f) {
  __hip_bfloat16 h = __float2bfloat16(f);
  return *reinterpret_cast<u16*>(&h);
}
__device__ inline float b2f(u16 u) {
  __hip_bfloat16 h;
  *reinterpret_cast<u16*>(&h) = u;
  return __bfloat162float(h);
}
__device__ inline bf16x8 ld8(const u16* p) {
  return *reinterpret_cast<const bf16x8*>(p);
}
__device__ inline f32x4 mfma16(bf16x8 a, bf16x8 b, f32x4 c) {
  return __builtin_amdgcn_mfma_f32_16x16x32_bf16(a, b, c, 0, 0, 0);
}

// plain (L2-cacheable) global->LDS DMA, 16B/lane
__device__ inline void gload_lds16(const void* g, void* l) {
  __builtin_amdgcn_global_load_lds((const AS1 void*)g, (AS3 void*)l, 16, 0, 0);
}
// agent-scope global->LDS DMA (CPol SC1 only = device scope): bypasses the
// potentially-stale per-XCD L2 but is served by the LLC (agent coherence pt).
__device__ inline void gload_lds16c(const void* g, void* l) {
  __builtin_amdgcn_global_load_lds((const AS1 void*)g, (AS3 void*)l, 16, 0, 0x10);
}

// relaxed agent-scope (LLC write-through) u16 store
__device__ inline void st16(u16* p, u16 v) {
  __hip_atomic_store(p, v, __ATOMIC_RELAXED, __HIP_MEMORY_SCOPE_AGENT);
}

// 64 lanes watch 64 packed epoch flags; exit when all >= target
__device__ inline void poll64(unsigned* f, unsigned target, int lane) {
  unsigned* p = f + lane;
  while (true) {
    unsigned v = __hip_atomic_load(p, __ATOMIC_RELAXED, __HIP_MEMORY_SCOPE_AGENT);
    if (__all((int)(v >= target))) break;
    __builtin_amdgcn_s_sleep(1);
  }
}

// combined two-flag-array poll (one LLC round trip for both conditions)
__device__ inline void poll64x2(unsigned* fa, unsigned ta, unsigned* fb,
                                unsigned tb, int lane) {
  unsigned* pa = fa + lane;
  unsigned* pb = fb + lane;
  while (true) {
    unsigned va = __hip_atomic_load(pa, __ATOMIC_RELAXED, __HIP_MEMORY_SCOPE_AGENT);
    unsigned vb = __hip_atomic_load(pb, __ATOMIC_RELAXED, __HIP_MEMORY_SCOPE_AGENT);
    if (__all((int)(va >= ta) & (int)(vb >= tb))) break;
    __builtin_amdgcn_s_sleep(1);
  }
}

// ---------------- elementwise helpers ----------------

__global__ void castk(const float* __restrict__ src, u16* __restrict__ dst, int n) {
  int i = blockIdx.x * 256 + threadIdx.x;
  if (i < n) dst[i] = f2b(src[i]);
}

__global__ void init_h(const float* __restrict__ h0, float* __restrict__ h32_0,
                       float* __restrict__ h32_1, u16* __restrict__ hring_s3,
                       u16* __restrict__ hbf_1) {
  int i = blockIdx.x * 256 + threadIdx.x;
  if (i < 32 * 1024) {
    int b = i >> 10, j = i & 1023;
    float v0 = h0[(b * 2 + 0) * 1024 + j];
    float v1 = h0[(b * 2 + 1) * 1024 + j];
    h32_0[i] = v0; hring_s3[i] = f2b(v0);  // layer0 h(-1) lives in ring slot 3
    h32_1[i] = v1; hbf_1[i] = f2b(v1);
  }
}

__global__ void final_h(const float* __restrict__ h32_0, const float* __restrict__ h32_1,
                        float* __restrict__ out) {
  int i = blockIdx.x * 256 + threadIdx.x;
  if (i < 32 * 1024) {
    int b = i >> 10, j = i & 1023;
    out[(b * 2 + 0) * 1024 + j] = h32_0[i];
    out[(b * 2 + 1) * 1024 + j] = h32_1[i];
  }
}

// ---------------- big NT GEMM: C[m,n] = sum_k A[m,k]*B[n,k] + bias[n] ----------------
// MODE 0: fp32 store at [m][n].  MODE 2: bf16 store transposed-to-step-major:
// m = b*512 + t  ->  store at [(t*32 + b)][n]  (A buffers for the recurrence).

template <int MODE>
__global__ __launch_bounds__(256, 2) void gemm_nt(const u16* __restrict__ A,
                                                  const u16* __restrict__ B,
                                                  const float* __restrict__ bias,
                                                  void* __restrict__ Cout,
                                                  int M, int N, int K) {
  __shared__ __align__(16) u16 As[128 * 32];
  __shared__ __align__(16) u16 Bs[128 * 32];
  const int tid = threadIdx.x;
  const int lane = tid & 63;
  const int wave = tid >> 6;
  const int tilesN = N >> 7;
  const int bm = blockIdx.x / tilesN, bn = blockIdx.x % tilesN;
  const int wr = (wave >> 1) << 6, wc = (wave & 1) << 6;
  const int la = lane & 15, kg = lane >> 4;
  f32x4 acc[4][4] = {};
  const int srow = tid >> 2, skoff = (tid & 3) << 3;
  const u16* Ap = A + (size_t)(bm * 128 + srow) * K + skoff;
  const u16* Bp = B + (size_t)(bn * 128 + srow) * K + skoff;
  for (int k0 = 0; k0 < K; k0 += 32) {
    gload_lds16(Ap + k0,            As + tid * 8);
    gload_lds16(Ap + (size_t)64 * K + k0, As + 2048 + tid * 8);
    gload_lds16(Bp + k0,            Bs + tid * 8);
    gload_lds16(Bp + (size_t)64 * K + k0, Bs + 2048 + tid * 8);
    __syncthreads();
    bf16x8 af[4], bfr[4];
#pragma unroll
    for (int i = 0; i < 4; ++i) af[i] = ld8(As + (wr + i * 16 + la) * 32 + kg * 8);
#pragma unroll
    for (int j = 0; j < 4; ++j) bfr[j] = ld8(Bs + (wc + j * 16 + la) * 32 + kg * 8);
#pragma unroll
    for (int i = 0; i < 4; ++i)
#pragma unroll
      for (int j = 0; j < 4; ++j)
        acc[i][j] = mfma16(af[i], bfr[j], acc[i][j]);
    __syncthreads();
  }
  const int rbase = bm * 128 + wr + kg * 4;
  const int cbase = bn * 128 + wc + la;
#pragma unroll
  for (int i = 0; i < 4; ++i) {
#pragma unroll
    for (int j = 0; j < 4; ++j) {
      int col = cbase + j * 16;
      float bv = bias[col];
#pragma unroll
      for (int e = 0; e < 4; ++e) {
        int row = rbase + i * 16 + e;
        float v = acc[i][j][e] + bv;
        if (MODE == 0) {
          ((float*)Cout)[(size_t)row * N + col] = v;
        } else {
          int tt = row & 511, bb = row >> 9;
          ((u16*)Cout)[((size_t)(tt * 32 + bb)) * N + col] = f2b(v);
        }
      }
    }
  }
}

// ---------------- fused two-layer persistent GRU recurrence, v2 ----------------
// 256 blocks x 128 threads: layer = bid>>7, rt = (bid>>6)&1, colT = bid&63.
// Layer0: reads h(t-1) from ring slot (t-1)&3, writes h(t) to slot t&3 with
//   the same st16+drain+fl2 publish as before. Gates on fl1(L1) >= t-3 so a
//   slot is never overwritten before layer1 finished staging it (lag <= 4).
// Layer1: combined-poll {fl2(L1) >= t, fl2(L0) >= t+1}, DMAs h0(t) (ring
//   slot t&3) -> LDSx and h1(t-1) -> LDSh back-to-back. Stage-1 x-weights
//   come from LDS (WXZ, staged once); wgx stays in VGPRs.

__global__ __launch_bounds__(128, 1) void gru_pipe2(
    const u16* __restrict__ Wz0, const u16* __restrict__ Wr0, const u16* __restrict__ Wg0,
    const u16* __restrict__ Wz1, const u16* __restrict__ Wr1, const u16* __restrict__ Wg1,
    const u16* __restrict__ Wzx1, const u16* __restrict__ Wrx1, const u16* __restrict__ Wgx1,
    const float* __restrict__ bz1, const float* __restrict__ br1, const float* __restrict__ bg1,
    const u16* __restrict__ Az, const u16* __restrict__ Ar, const u16* __restrict__ Ag,
    u16* __restrict__ hring, u16* __restrict__ hist1,
    float* __restrict__ h32_0, float* __restrict__ h32_1,
    u16* __restrict__ hbf1,
    u16* __restrict__ rhbf0, u16* __restrict__ rhbf1,
    unsigned* __restrict__ flags, int S) {
  __shared__ __align__(16) u16 LDSh[16 * 1024];
  __shared__ __align__(16) u16 LDSx[16 * 1024];
  __shared__ __align__(16) u16 WXZ[32 * 1024];  // [wave][ks<32][lane][8] bf16
  __shared__ float zloc[256];
  __shared__ float h32loc[256];
  __shared__ float part[256];
  const int tid = threadIdx.x, wave = tid >> 6, lane = tid & 63;
  const int la = lane & 15, kg = lane >> 4;
  const int sw = la & 7;
  const int layer = blockIdx.x >> 7;
  const int rt = (blockIdx.x >> 6) & 1, colT = blockIdx.x & 63;
  const int col = colT * 16 + la;
  unsigned* myfl1 = flags + (layer * 2 + rt) * 128;  // stage1 (rhbf ready)
  unsigned* myfl2 = myfl1 + 64;                      // stage2 (h ready)
  unsigned* l1fl1 = flags + (2 + rt) * 128;          // layer1 stage1 (ring-read done)
  unsigned* l0fl2 = flags + rt * 128 + 64;           // layer0 h ready

  float* h32g = layer ? h32_1 : h32_0;
  u16* rhbf = layer ? rhbf1 : rhbf0;

  for (int i = tid; i < 256; i += 128)
    h32loc[i] = h32g[(rt * 16 + (i >> 4)) * 1024 + colT * 16 + (i & 15)];

  // recurrent weight slices -> VGPRs (wave0: z, wave1: r; g split-K)
  const u16* w1p = (wave ? (layer ? Wr1 : Wr0) : (layer ? Wz1 : Wz0)) +
                   (size_t)col * 1024 + kg * 8;
  const u16* wgp = (layer ? Wg1 : Wg0) + (size_t)col * 1024 + wave * 512 + kg * 8;
  bf16x8 wzr[32], wg[16];
#pragma unroll
  for (int ks = 0; ks < 32; ++ks) wzr[ks] = ld8(w1p + ks * 32);
#pragma unroll
  for (int ks = 0; ks < 16; ++ks) wg[ks] = ld8(wgp + ks * 32);

  // layer1-only: stage-1 x-weights -> LDS (WXZ), stage-2 x-weights -> VGPRs
  bf16x8 wgx[16];
  float b1v = 0.f, bgv = 0.f;
  if (layer) {
    const u16* wxp = (wave ? Wrx1 : Wzx1) + (size_t)col * 1024 + kg * 8;
#pragma unroll
    for (int ks = 0; ks < 32; ++ks) {
      bf16x8 w = ld8(wxp + ks * 32);
      *reinterpret_cast<bf16x8*>(&WXZ[((wave * 32 + ks) * 64 + lane) * 8]) = w;
    }
    const u16* wgxp = Wgx1 + (size_t)col * 1024 + wave * 512 + kg * 8;
#pragma unroll
    for (int ks = 0; ks < 16; ++ks) wgx[ks] = ld8(wgxp + ks * 32);
    b1v = wave ? br1[col] : bz1[col];
    bgv = bg1[col];
  }
  __syncthreads();  // h32loc + WXZ staged

  const u16* wxl = WXZ + (wave * 32 * 64 + lane) * 8;  // stage-1 x-weight base
  const u16* A1 = wave ? Ar : Az;
  const u16* rsrc = rhbf + rt * 16384;
  const int rowb = rt * 16 + kg * 4;  // batch-row base of this lane's outputs

  for (int t = 0; t < S; ++t) {
    u16 a1raw[4] = {0, 0, 0, 0};
    u16 agraw[4] = {0, 0, 0, 0};
    if (!layer) {
      // A prefetch: independent of flags, overlaps poll+staging
      const u16* A1t = A1 + (size_t)t * 32768;
#pragma unroll
      for (int e = 0; e < 4; ++e) a1raw[e] = A1t[(rowb + e) * 1024 + col];
      if (wave == 0) {
        const u16* Agt = Ag + (size_t)t * 32768;
#pragma unroll
        for (int e = 0; e < 4; ++e) agraw[e] = Agt[(rowb + e) * 1024 + col];
      }
      // own h(t-1) ready + ring slot t&3 free (layer1 staged step t-4)
      unsigned tb = t >= 4 ? (unsigned)(t - 3) : 0u;
      poll64x2(myfl2, (unsigned)t, l1fl1, tb, lane);
    } else {
      // h1(t-1) ready + h0(t) ready; then both tiles' DMAs back-to-back
      poll64x2(myfl2, (unsigned)t, l0fl2, (unsigned)(t + 1), lane);
      const u16* xs = hring + (t & 3) * 32768 + rt * 16384;
#pragma unroll
      for (int i = 0; i < 16; ++i) {
        int u = i * 2 + wave, r = u >> 1, c = u & 1;
        gload_lds16c(xs + r * 1024 + c * 512 + (lane ^ (r & 7)) * 8,
                     LDSx + r * 1024 + c * 512 + lane * 8);
      }
    }
    // ---- stage 1: z (wave0) and r (wave1) ----
    const u16* hs = layer ? (hbf1 + rt * 16384)
                          : (hring + ((t + 3) & 3) * 32768 + rt * 16384);
#pragma unroll
    for (int i = 0; i < 16; ++i) {
      int u = i * 2 + wave, r = u >> 1, c = u & 1;
      gload_lds16c(hs + r * 1024 + c * 512 + (lane ^ (r & 7)) * 8,
                   LDSh + r * 1024 + c * 512 + lane * 8);
    }
    __syncthreads();  // drains all DMA (vmcnt) for both waves
    f32x4 p0 = {0.f, 0.f, 0.f, 0.f}, p1 = {0.f, 0.f, 0.f, 0.f};
#pragma unroll
    for (int ks = 0; ks < 32; ks += 2) {
      p0 = mfma16(ld8(LDSh + la * 1024 + (((ks * 4 + kg) ^ sw) << 3)), wzr[ks], p0);
      p1 = mfma16(ld8(LDSh + la * 1024 + ((((ks + 1) * 4 + kg) ^ sw) << 3)), wzr[ks + 1], p1);
    }
    if (layer) {
#pragma unroll
      for (int ks = 0; ks < 32; ks += 2) {
        p0 = mfma16(ld8(LDSx + la * 1024 + (((ks * 4 + kg) ^ sw) << 3)),
                    ld8(wxl + ks * 512), p0);
        p1 = mfma16(ld8(LDSx + la * 1024 + ((((ks + 1) * 4 + kg) ^ sw) << 3)),
                    ld8(wxl + (ks + 1) * 512), p1);
      }
    }
    if (wave == 0) {
#pragma unroll
      for (int e = 0; e < 4; ++e) {
        float pre = p0[e] + p1[e] + (layer ? b1v : b2f(a1raw[e]));
        zloc[(kg * 4 + e) * 16 + la] = 1.f / (1.f + __expf(-pre));
      }
    } else {
#pragma unroll
      for (int e = 0; e < 4; ++e) {
        float pre = p0[e] + p1[e] + (layer ? b1v : b2f(a1raw[e]));
        float rv = 1.f / (1.f + __expf(-pre));
        st16(&rhbf[(rowb + e) * 1024 + col], f2b(rv * h32loc[(kg * 4 + e) * 16 + la]));
      }
      __builtin_amdgcn_s_waitcnt(0);  // r-tile drained to LLC
      if (lane == 0)
        __hip_atomic_store(&myfl1[colT], (unsigned)(t + 1), __ATOMIC_RELAXED,
                           __HIP_MEMORY_SCOPE_AGENT);
    }
    __syncthreads();  // wave0 must not DMA over LDSh while wave1 still reads it
    // ---- stage 2: g (split-K over both waves) + h update (wave0) ----
    poll64(myfl1, (unsigned)(t + 1), lane);
#pragma unroll
    for (int i = 0; i < 16; ++i) {
      int u = i * 2 + wave, r = u >> 1, c = u & 1;
      gload_lds16c(rsrc + r * 1024 + c * 512 + (lane ^ (r & 7)) * 8,
                   LDSh + r * 1024 + c * 512 + lane * 8);
    }
    __syncthreads();
    f32x4 q0 = {0.f, 0.f, 0.f, 0.f}, q1 = {0.f, 0.f, 0.f, 0.f};
#pragma unroll
    for (int ks = 0; ks < 16; ks += 2) {
      q0 = mfma16(ld8(LDSh + la * 1024 + (((wave * 64 + ks * 4 + kg) ^ sw) << 3)), wg[ks], q0);
      q1 = mfma16(ld8(LDSh + la * 1024 + (((wave * 64 + (ks + 1) * 4 + kg) ^ sw) << 3)), wg[ks + 1], q1);
    }
    if (layer) {
#pragma unroll
      for (int ks = 0; ks < 16; ks += 2) {
        q0 = mfma16(ld8(LDSx + la * 1024 + (((wave * 64 + ks * 4 + kg) ^ sw) << 3)), wgx[ks], q0);
        q1 = mfma16(ld8(LDSx + la * 1024 + (((wave * 64 + (ks + 1) * 4 + kg) ^ sw) << 3)), wgx[ks + 1], q1);
      }
    }
    if (wave == 1) {
#pragma unroll
      for (int e = 0; e < 4; ++e) part[lane * 4 + e] = q0[e] + q1[e];
    }
    __syncthreads();
    if (wave == 0) {
      float hnv[4];
      u16 hbv[4];
      u16* hdst = layer ? hbf1 : (hring + (t & 3) * 32768);
#pragma unroll
      for (int e = 0; e < 4; ++e) {
        int li = (kg * 4 + e) * 16 + la;
        float gs = q0[e] + q1[e] + part[lane * 4 + e] + (layer ? bgv : b2f(agraw[e]));
        float ex = __expf(2.f * gs);
        float g = 1.f - 2.f / (ex + 1.f);  // tanh, inf-safe
        float z = zloc[li];
        float hn = (1.f - z) * h32loc[li] + z * g;
        h32loc[li] = hn;
        hnv[e] = hn;
        hbv[e] = f2b(hn);
        st16(&hdst[(rowb + e) * 1024 + col], hbv[e]);  // critical-path publish
      }
      __builtin_amdgcn_s_waitcnt(0);  // h-tile drained to LLC
      if (lane == 0)
        __hip_atomic_store(&myfl2[colT], (unsigned)(t + 1), __ATOMIC_RELAXED,
                           __HIP_MEMORY_SCOPE_AGENT);
      // off-critical-path: layer1 history (read only by the output GEMM;
      // kernel-boundary flush provides visibility) + final-state snapshot
#pragma unroll
      for (int e = 0; e < 4; ++e) {
        if (layer) hist1[((size_t)(rowb + e) * S + t) * 1024 + col] = hbv[e];
        if (t == S - 1) h32g[(rowb + e) * 1024 + col] = hnv[e];
      }
    }
    __syncthreads();  // next stage1 DMA must not overwrite LDSh/LDSx early
  }
}

// ---------------- host ----------------

extern "C" void kernel_launch(void* const* d_in, const int* in_sizes, int n_in,
                              void* d_out, int out_size, void* d_ws, size_t ws_size,
                              hipStream_t stream) {
  (void)in_sizes; (void)n_in; (void)out_size;
  const float* x   = (const float*)d_in[0];
  const float* h0  = (const float*)d_in[1];
  const float* Wzx = (const float*)d_in[2];
  const float* bz  = (const float*)d_in[3];
  const float* Wzh = (const float*)d_in[4];
  const float* Wrx = (const float*)d_in[5];
  const float* br  = (const float*)d_in[6];
  const float* Wrh = (const float*)d_in[7];
  const float* Wgx = (const float*)d_in[8];
  const float* bg  = (const float*)d_in[9];
  const float* Wgh = (const float*)d_in[10];
  const float* Wo  = (const float*)d_in[11];
  const float* bo  = (const float*)d_in[12];
  float* out = (float*)d_out;
  char* ws = (char*)d_ws;

  const size_t MB = 1024 * 1024;
  size_t o = 4096;  // flags live in [0,4096): per-(layer,rt) fl1/fl2
  u16* wWzx = (u16*)(ws + o); o += 4 * MB;   // [L=2][1024][1024] bf16
  u16* wWzh = (u16*)(ws + o); o += 4 * MB;
  u16* wWrx = (u16*)(ws + o); o += 4 * MB;
  u16* wWrh = (u16*)(ws + o); o += 4 * MB;
  u16* wWgx = (u16*)(ws + o); o += 4 * MB;
  u16* wWgh = (u16*)(ws + o); o += 4 * MB;
  u16* wWo  = (u16*)(ws + o); o += 2 * MB;
  u16* Az    = (u16*)(ws + o); o += 32 * MB;  // [512][32][1024] bf16 step-major
  u16* Ar    = (u16*)(ws + o); o += 32 * MB;
  u16* Ag    = (u16*)(ws + o); o += 32 * MB;
  u16* hring = (u16*)(ws + o); o += 256 * 1024;  // [4][32][1024] layer0 h ring
  u16* xbf   = (u16*)(ws + o); o += 32 * MB;  // x bf16; later reused as hist1
  float* h32_0 = (float*)(ws + o); o += 131072;
  float* h32_1 = (float*)(ws + o); o += 131072;
  u16* hbf_1 = (u16*)(ws + o); o += 65536;
  u16* rhbf0 = (u16*)(ws + o); o += 65536;
  u16* rhbf1 = (u16*)(ws + o); o += 65536;

  if (ws_size < o) {
    fprintf(stderr, "[gru] INSUFFICIENT WORKSPACE ws=%zu need=%zu\n", ws_size, o);
    return;
  }
  unsigned* flags = (unsigned*)ws;
  hipMemsetAsync(ws, 0, 4096, stream);

  // casts
  castk<<<dim3(8192), dim3(256), 0, stream>>>(Wzx, wWzx, 2097152);
  castk<<<dim3(8192), dim3(256), 0, stream>>>(Wzh, wWzh, 2097152);
  castk<<<dim3(8192), dim3(256), 0, stream>>>(Wrx, wWrx, 2097152);
  castk<<<dim3(8192), dim3(256), 0, stream>>>(Wrh, wWrh, 2097152);
  castk<<<dim3(8192), dim3(256), 0, stream>>>(Wgx, wWgx, 2097152);
  castk<<<dim3(8192), dim3(256), 0, stream>>>(Wgh, wWgh, 2097152);
  castk<<<dim3(4096), dim3(256), 0, stream>>>(Wo, wWo, 1048576);
  castk<<<dim3(65536), dim3(256), 0, stream>>>(x, xbf, 16777216);
  init_h<<<dim3(128), dim3(256), 0, stream>>>(h0, h32_0, h32_1,
                                              hring + 3 * 32768, hbf_1);

  // layer0 input projections (step-major output)
  gemm_nt<2><<<dim3(1024), dim3(256), 0, stream>>>(xbf, wWzx, bz, Az, 16384, 1024, 1024);
  gemm_nt<2><<<dim3(1024), dim3(256), 0, stream>>>(xbf, wWrx, br, Ar, 16384, 1024, 1024);
  gemm_nt<2><<<dim3(1024), dim3(256), 0, stream>>>(xbf, wWgx, bg, Ag, 16384, 1024, 1024);

  // fused two-layer recurrence pipeline (hist1 lives in xbf region)
  gru_pipe2<<<dim3(256), dim3(128), 0, stream>>>(
      wWzh, wWrh, wWgh,
      wWzh + 1048576, wWrh + 1048576, wWgh + 1048576,
      wWzx + 1048576, wWrx + 1048576, wWgx + 1048576,
      bz + 1024, br + 1024, bg + 1024,
      Az, Ar, Ag, hring, xbf,
      h32_0, h32_1, hbf_1, rhbf0, rhbf1,
      flags, 512);

  // output projection
  gemm_nt<0><<<dim3(1024), dim3(256), 0, stream>>>(xbf, wWo, bo, out, 16384, 1024, 1024);

  // final hidden states
  final_h<<<dim3(128), dim3(256), 0, stream>>>(h32_0, h32_1, out + 16777216);
}